// Round 1
// baseline (1498.636 us; speedup 1.0000x reference)
//
#include <hip/hip_runtime.h>
#include <math.h>

// Problem constants
#define DIMC   512
#define HEADS  8
#define SLOTS  112
#define HD     64          // DIMC/HEADS
#define NROWS  16384       // B*S = 32*512
#define RADIUSF 16.0f

// ---------------------------------------------------------------------------
// Generic tiled fp32 GEMM: C(MxN) = A(MxK) @ B(NxK)^T (+ bias[col])
// Row-major with leading dims lda/ldb/ldc; per-blockIdx.z flat element
// offsets aZ/bZ/cZ (used for the per-head W2 precompute).
// 64x64 block tile, BK=16, 256 threads, 4x4 micro-tile per thread.
// All K used here are multiples of 16, so no K-edge guard is needed.
// ---------------------------------------------------------------------------
__global__ __launch_bounds__(256)
void gemm_abt(const float* __restrict__ A, int lda,
              const float* __restrict__ B, int ldb,
              float* __restrict__ C, int ldc,
              int M, int N, int K,
              const float* __restrict__ bias,
              int aZ, int bZ, int cZ)
{
    __shared__ float As[16][68];   // [k][m], padded row to 68 floats (16B-aligned rows)
    __shared__ float Bs[16][68];   // [k][n]
    A += (size_t)blockIdx.z * aZ;
    B += (size_t)blockIdx.z * bZ;
    C += (size_t)blockIdx.z * cZ;
    const int m0 = blockIdx.y * 64;
    const int n0 = blockIdx.x * 64;
    const int tid = threadIdx.x;
    const int tm = tid >> 4;            // 0..15
    const int tn = tid & 15;            // 0..15
    const int lr = tid >> 2;            // 0..63  (tile row for loads)
    const int lc = (tid & 3) << 2;      // 0,4,8,12 (k-col for loads)

    float acc[4][4] = {};

    for (int k0 = 0; k0 < K; k0 += 16) {
        float4 av = make_float4(0.f, 0.f, 0.f, 0.f);
        float4 bv = make_float4(0.f, 0.f, 0.f, 0.f);
        const int am = m0 + lr;
        if (am < M) av = *(const float4*)(A + (size_t)am * lda + k0 + lc);
        const int bn = n0 + lr;
        if (bn < N) bv = *(const float4*)(B + (size_t)bn * ldb + k0 + lc);
        As[lc + 0][lr] = av.x; As[lc + 1][lr] = av.y;
        As[lc + 2][lr] = av.z; As[lc + 3][lr] = av.w;
        Bs[lc + 0][lr] = bv.x; Bs[lc + 1][lr] = bv.y;
        Bs[lc + 2][lr] = bv.z; Bs[lc + 3][lr] = bv.w;
        __syncthreads();
        #pragma unroll
        for (int k = 0; k < 16; ++k) {
            float a[4], b[4];
            #pragma unroll
            for (int i = 0; i < 4; ++i) a[i] = As[k][tm * 4 + i];
            #pragma unroll
            for (int j = 0; j < 4; ++j) b[j] = Bs[k][tn * 4 + j];
            #pragma unroll
            for (int i = 0; i < 4; ++i)
                #pragma unroll
                for (int j = 0; j < 4; ++j)
                    acc[i][j] += a[i] * b[j];
        }
        __syncthreads();
    }

    #pragma unroll
    for (int i = 0; i < 4; ++i) {
        const int row = m0 + tm * 4 + i;
        if (row >= M) continue;
        #pragma unroll
        for (int j = 0; j < 4; ++j) {
            const int col = n0 + tn * 4 + j;
            if (col < N) {
                float v = acc[i][j];
                if (bias) v += bias[col];
                C[(size_t)row * ldc + col] = v;
            }
        }
    }
}

// ---------------------------------------------------------------------------
// Small helpers
// ---------------------------------------------------------------------------
__device__ __forceinline__ float block_sum_256(float v, float* red)
{
    #pragma unroll
    for (int off = 32; off; off >>= 1) v += __shfl_down(v, off, 64);
    const int lane = threadIdx.x & 63, wid = threadIdx.x >> 6;
    __syncthreads();                    // protect red[] from previous call
    if (lane == 0) red[wid] = v;
    __syncthreads();
    return red[0] + red[1] + red[2] + red[3];
}

__global__ void zero_small(float* p, int n)
{
    int i = blockIdx.x * blockDim.x + threadIdx.x;
    if (i < n) p[i] = 0.f;
}

// key_norm: l2-normalize each 64-wide row of key_mem (896 rows)
__global__ void prep_key_norm(const float* __restrict__ km, float* __restrict__ kn)
{
    const int row = blockIdx.x;
    const int lane = threadIdx.x;      // 64 threads
    float v = km[(size_t)row * HD + lane];
    float s = v * v;
    #pragma unroll
    for (int off = 32; off; off >>= 1) s += __shfl_down(s, off, 64);
    s = __shfl(s, 0, 64);
    const float inv = 1.f / fmaxf(sqrtf(s), 1e-12f);
    kn[(size_t)row * HD + lane] = v * inv;
}

// value_norm (l2 rows of value_mem) + vmT (raw transpose for aud GEMM)
__global__ void prep_value_norm(const float* __restrict__ vm,
                                float* __restrict__ vn, float* __restrict__ vmT)
{
    const int row = blockIdx.x;        // 0..111
    const int tid = threadIdx.x;       // 256
    __shared__ float red[4];
    const float v0 = vm[(size_t)row * DIMC + tid];
    const float v1 = vm[(size_t)row * DIMC + 256 + tid];
    const float tot = block_sum_256(v0 * v0 + v1 * v1, red);
    const float inv = 1.f / fmaxf(sqrtf(tot), 1e-12f);
    vn[(size_t)row * DIMC + tid]        = v0 * inv;
    vn[(size_t)row * DIMC + 256 + tid]  = v1 * inv;
    vmT[(size_t)tid * SLOTS + row]         = v0;
    vmT[(size_t)(256 + tid) * SLOTS + row] = v1;
}

// contrastive = 0.5 * sum |I - vn@vn^T|
__global__ void contrastive_kernel(const float* __restrict__ vn, float* __restrict__ outc)
{
    __shared__ float vni[DIMC];
    __shared__ float red[2];
    const int i = blockIdx.x, tid = threadIdx.x;   // 128 threads
    for (int d = tid; d < DIMC; d += 128) vni[d] = vn[(size_t)i * DIMC + d];
    __syncthreads();
    float t = 0.f;
    if (tid < SLOTS) {
        const float* r = vn + (size_t)tid * DIMC;
        float dot = 0.f;
        for (int d = 0; d < DIMC; ++d) dot += vni[d] * r[d];
        const float delta = (tid == i) ? 1.f : 0.f;
        t = fabsf(delta - dot);
    }
    #pragma unroll
    for (int off = 32; off; off >>= 1) t += __shfl_down(t, off, 64);
    if ((tid & 63) == 0) red[tid >> 6] = t;
    __syncthreads();
    if (tid == 0) atomicAdd(outc, 0.5f * (red[0] + red[1]));
}

// Per-row: per-head l2norm of eq, sims vs key_norm, per-head softmax -> key_add
__global__ __launch_bounds__(256)
void key_address(const float* __restrict__ eq, const float* __restrict__ kn,
                 float* __restrict__ key_add)
{
    const int r = blockIdx.x, tid = threadIdx.x;
    __shared__ float eqs[DIMC];
    __shared__ float hinv[HEADS];
    eqs[tid]       = eq[(size_t)r * DIMC + tid];
    eqs[tid + 256] = eq[(size_t)r * DIMC + 256 + tid];
    __syncthreads();
    if (tid < HEADS) {
        float s = 0.f;
        for (int j = 0; j < HD; ++j) { const float v = eqs[tid * HD + j]; s += v * v; }
        hinv[tid] = 1.f / fmaxf(sqrtf(s), 1e-12f);
    }
    __syncthreads();

    const int g  = tid >> 5;    // head 0..7 (one 32-lane subgroup per head)
    const int li = tid & 31;
    const float scale = hinv[g] * RADIUSF;
    const float* eh = eqs + g * HD;

    float sims[4] = { -1e30f, -1e30f, -1e30f, -1e30f };
    #pragma unroll
    for (int u = 0; u < 4; ++u) {
        const int s = li + u * 32;
        if (s < SLOTS) {
            const float* kr = kn + (size_t)(g * SLOTS + s) * HD;
            float d = 0.f;
            #pragma unroll
            for (int j = 0; j < HD; j += 4) {
                const float4 k4 = *(const float4*)(kr + j);
                const float4 e4 = *(const float4*)(eh + j);
                d += k4.x * e4.x + k4.y * e4.y + k4.z * e4.z + k4.w * e4.w;
            }
            sims[u] = d * scale;
        }
    }
    // softmax over this head's 112 slots, within the 32-lane subgroup
    float mx = fmaxf(fmaxf(sims[0], sims[1]), fmaxf(sims[2], sims[3]));
    #pragma unroll
    for (int off = 16; off; off >>= 1) mx = fmaxf(mx, __shfl_down(mx, off, 32));
    mx = __shfl(mx, 0, 32);
    float e[4]; float sum = 0.f;
    #pragma unroll
    for (int u = 0; u < 4; ++u) {
        const int s = li + u * 32;
        e[u] = (s < SLOTS) ? __expf(sims[u] - mx) : 0.f;
        sum += e[u];
    }
    #pragma unroll
    for (int off = 16; off; off >>= 1) sum += __shfl_down(sum, off, 32);
    sum = __shfl(sum, 0, 32);
    const float invs = 1.f / sum;
    #pragma unroll
    for (int u = 0; u < 4; ++u) {
        const int s = li + u * 32;
        if (s < SLOTS)
            key_add[(size_t)r * (HEADS * SLOTS) + g * SLOTS + s] = e[u] * invs;
    }
}

// vir_pre -> LN(g2,b2) -> +query -> LN(g1,b1) -> out_te
__global__ __launch_bounds__(256)
void vir_te_kernel(const float* __restrict__ vir_pre, const float* __restrict__ query,
                   const float* __restrict__ g1, const float* __restrict__ b1,
                   const float* __restrict__ g2, const float* __restrict__ b2,
                   float* __restrict__ out_te)
{
    const int r = blockIdx.x, tid = threadIdx.x;
    __shared__ float red[4];
    float x0 = vir_pre[(size_t)r * DIMC + tid];
    float x1 = vir_pre[(size_t)r * DIMC + 256 + tid];
    float mu = block_sum_256(x0 + x1, red) * (1.f / DIMC);
    float d0 = x0 - mu, d1 = x1 - mu;
    float var = block_sum_256(d0 * d0 + d1 * d1, red) * (1.f / DIMC);
    float rstd = rsqrtf(var + 1e-5f);
    const float v0 = d0 * rstd * g2[tid] + b2[tid];
    const float v1 = d1 * rstd * g2[tid + 256] + b2[tid + 256];
    const float q0 = query[(size_t)r * DIMC + tid];
    const float q1 = query[(size_t)r * DIMC + 256 + tid];
    float y0 = q0 + v0, y1 = q1 + v1;
    mu = block_sum_256(y0 + y1, red) * (1.f / DIMC);
    d0 = y0 - mu; d1 = y1 - mu;
    var = block_sum_256(d0 * d0 + d1 * d1, red) * (1.f / DIMC);
    rstd = rsqrtf(var + 1e-5f);
    out_te[(size_t)r * DIMC + tid]       = d0 * rstd * g1[tid] + b1[tid];
    out_te[(size_t)r * DIMC + 256 + tid] = d1 * rstd * g1[tid + 256] + b1[tid + 256];
}

// l2-normalize 512-wide rows in place (ev -> evn)
__global__ __launch_bounds__(256)
void l2norm_rows(float* __restrict__ x)
{
    const int r = blockIdx.x, tid = threadIdx.x;
    __shared__ float red[4];
    const float v0 = x[(size_t)r * DIMC + tid];
    const float v1 = x[(size_t)r * DIMC + 256 + tid];
    const float s = block_sum_256(v0 * v0 + v1 * v1, red);
    const float inv = 1.f / fmaxf(sqrtf(s), 1e-12f);
    x[(size_t)r * DIMC + tid]       = v0 * inv;
    x[(size_t)r * DIMC + 256 + tid] = v1 * inv;
}

// softmax(16*x) over 112 slots, in place
__global__ __launch_bounds__(128)
void value_softmax(float* __restrict__ vs)
{
    const int r = blockIdx.x, tid = threadIdx.x;   // 128 threads
    __shared__ float red[2];
    const float v = (tid < SLOTS) ? vs[(size_t)r * SLOTS + tid] * RADIUSF : -1e30f;
    float m = v;
    #pragma unroll
    for (int off = 32; off; off >>= 1) m = fmaxf(m, __shfl_down(m, off, 64));
    if ((tid & 63) == 0) red[tid >> 6] = m;
    __syncthreads();
    m = fmaxf(red[0], red[1]);
    const float e = (tid < SLOTS) ? __expf(v - m) : 0.f;
    __syncthreads();
    float s = e;
    #pragma unroll
    for (int off = 32; off; off >>= 1) s += __shfl_down(s, off, 64);
    if ((tid & 63) == 0) red[tid >> 6] = s;
    __syncthreads();
    s = red[0] + red[1];
    if (tid < SLOTS) vs[(size_t)r * SLOTS + tid] = e / s;
}

// aud: cos/recon, LN(g3,b3), +query, LN(g1,b1) -> out_tr
__global__ __launch_bounds__(256)
void aud_epilogue(const float* __restrict__ aud, const float* __restrict__ value,
                  const float* __restrict__ query,
                  const float* __restrict__ g1, const float* __restrict__ b1,
                  const float* __restrict__ g3, const float* __restrict__ b3,
                  float* __restrict__ out_tr, float* __restrict__ recon)
{
    const int r = blockIdx.x, tid = threadIdx.x;
    __shared__ float red[4];
    const float a0 = aud[(size_t)r * DIMC + tid];
    const float a1 = aud[(size_t)r * DIMC + 256 + tid];
    const float v0 = value[(size_t)r * DIMC + tid];
    const float v1 = value[(size_t)r * DIMC + 256 + tid];
    const float dot = block_sum_256(a0 * v0 + a1 * v1, red);
    const float na  = block_sum_256(a0 * a0 + a1 * a1, red);
    const float nv  = block_sum_256(v0 * v0 + v1 * v1, red);
    if (tid == 0) {
        const float cosv = dot / fmaxf(sqrtf(na) * sqrtf(nv), 1e-8f);
        atomicAdd(&recon[r >> 9], fabsf(1.f - cosv));
    }
    float mu = block_sum_256(a0 + a1, red) * (1.f / DIMC);
    float d0 = a0 - mu, d1 = a1 - mu;
    float var = block_sum_256(d0 * d0 + d1 * d1, red) * (1.f / DIMC);
    float rstd = rsqrtf(var + 1e-5f);
    const float w0 = d0 * rstd * g3[tid] + b3[tid];
    const float w1 = d1 * rstd * g3[tid + 256] + b3[tid + 256];
    const float q0 = query[(size_t)r * DIMC + tid];
    const float q1 = query[(size_t)r * DIMC + 256 + tid];
    float y0 = q0 + w0, y1 = q1 + w1;
    mu = block_sum_256(y0 + y1, red) * (1.f / DIMC);
    d0 = y0 - mu; d1 = y1 - mu;
    var = block_sum_256(d0 * d0 + d1 * d1, red) * (1.f / DIMC);
    rstd = rsqrtf(var + 1e-5f);
    out_tr[(size_t)r * DIMC + tid]       = d0 * rstd * g1[tid] + b1[tid];
    out_tr[(size_t)r * DIMC + 256 + tid] = d1 * rstd * g1[tid + 256] + b1[tid + 256];
}

// ---------------------------------------------------------------------------
// Launch
// ---------------------------------------------------------------------------
extern "C" void kernel_launch(void* const* d_in, const int* in_sizes, int n_in,
                              void* d_out, int out_size, void* d_ws, size_t ws_size,
                              hipStream_t stream)
{
    const float* query = (const float*)d_in[0];
    const float* value = (const float*)d_in[1];
    const float* keym  = (const float*)d_in[2];
    const float* vmem  = (const float*)d_in[3];
    const float* Wq    = (const float*)d_in[4];
    const float* bq    = (const float*)d_in[5];
    const float* Wv    = (const float*)d_in[6];
    const float* bv    = (const float*)d_in[7];
    const float* Wl    = (const float*)d_in[8];
    const float* bl    = (const float*)d_in[9];
    const float* g1    = (const float*)d_in[10];
    const float* b1    = (const float*)d_in[11];
    const float* g2    = (const float*)d_in[12];
    const float* b2    = (const float*)d_in[13];
    const float* g3    = (const float*)d_in[14];
    const float* b3    = (const float*)d_in[15];

    float* out    = (float*)d_out;
    float* out_te = out;                       // 16384*512
    float* out_tr = out + 8388608;             // 16384*512
    float* out_rc = out + 16777216;            // 32 recon + 1 contrastive

    // Workspace layout (floats). Total 33,923,072 floats = 135.7 MB.
    float* ws = (float*)d_ws;
    float* w_kn   = ws + 0;         //   896*64   = 57344
    float* w_vn   = ws + 57344;     //   112*512  = 57344
    float* w_vmT  = ws + 114688;    //   512*112  = 57344
    float* w_W2T  = ws + 172032;    //   512*896  = 458752
    float* w_eq   = ws + 630784;    // 16384*512  = 8388608 (reused as vir_pre)
    float* w_kadd = ws + 9019392;   // 16384*896  = 14680064
    float* w_ev   = ws + 23699456;  // 16384*512  = 8388608 (reused as aud)
    float* w_vs   = ws + 32088064;  // 16384*112  = 1835008

    // 0) zero recon+contrastive (d_out is poisoned before every call)
    zero_small<<<1, 64, 0, stream>>>(out_rc, 33);

    // 1) input-only precomputes
    prep_key_norm<<<896, 64, 0, stream>>>(keym, w_kn);
    prep_value_norm<<<112, 256, 0, stream>>>(vmem, w_vn, w_vmT);
    contrastive_kernel<<<112, 128, 0, stream>>>(w_vn, out_rc + 32);
    // W2T[o][h*112+s] = sum_d vm[s][d] * Wl[o][h*512+d]   (8 heads via grid.z)
    gemm_abt<<<dim3(2, 8, 8), 256, 0, stream>>>(
        Wl, 4096, vmem, DIMC, w_W2T, HEADS * SLOTS,
        DIMC, SLOTS, DIMC, nullptr, DIMC, 0, SLOTS);

    // 2) key addressing path
    gemm_abt<<<dim3(8, 256, 1), 256, 0, stream>>>(
        query, DIMC, Wq, DIMC, w_eq, DIMC,
        NROWS, DIMC, DIMC, bq, 0, 0, 0);
    key_address<<<NROWS, 256, 0, stream>>>(w_eq, w_kn, w_kadd);
    gemm_abt<<<dim3(8, 256, 1), 256, 0, stream>>>(            // vir_pre into eq buffer
        w_kadd, HEADS * SLOTS, w_W2T, HEADS * SLOTS, w_eq, DIMC,
        NROWS, DIMC, HEADS * SLOTS, bl, 0, 0, 0);
    vir_te_kernel<<<NROWS, 256, 0, stream>>>(w_eq, query, g1, b1, g2, b2, out_te);

    // 3) value addressing path
    gemm_abt<<<dim3(8, 256, 1), 256, 0, stream>>>(
        value, DIMC, Wv, DIMC, w_ev, DIMC,
        NROWS, DIMC, DIMC, bv, 0, 0, 0);
    l2norm_rows<<<NROWS, 256, 0, stream>>>(w_ev);
    gemm_abt<<<dim3(2, 256, 1), 256, 0, stream>>>(
        w_ev, DIMC, w_vn, DIMC, w_vs, SLOTS,
        NROWS, SLOTS, DIMC, nullptr, 0, 0, 0);
    value_softmax<<<NROWS, 128, 0, stream>>>(w_vs);
    gemm_abt<<<dim3(8, 256, 1), 256, 0, stream>>>(            // aud into ev buffer
        w_vs, SLOTS, w_vmT, SLOTS, w_ev, DIMC,
        NROWS, DIMC, SLOTS, nullptr, 0, 0, 0);
    aud_epilogue<<<NROWS, 256, 0, stream>>>(
        w_ev, value, query, g1, b1, g3, b3, out_tr, out_rc);
}

// Round 2
// 1002.302 us; speedup vs baseline: 1.4952x; 1.4952x over previous
//
#include <hip/hip_runtime.h>
#include <math.h>

// Problem constants
#define DIMC   512
#define HEADS  8
#define SLOTS  112
#define HD     64          // DIMC/HEADS
#define NROWS  16384       // B*S = 32*512
#define RADIUSF 16.0f

// ---------------------------------------------------------------------------
// Generic tiled fp32 GEMM: C(MxN) = A(MxK) @ B(NxK)^T (+ bias[col])
// Row-major with leading dims lda/ldb/ldc; per-blockIdx.z flat element
// offsets aZ/bZ/cZ (used for batched/per-head variants).
// 64x64 block tile, BK=16, 256 threads, 4x4 micro-tile per thread.
// All K used here are multiples of 16, so no K-edge guard is needed.
// ---------------------------------------------------------------------------
__global__ __launch_bounds__(256)
void gemm_abt(const float* __restrict__ A, int lda,
              const float* __restrict__ B, int ldb,
              float* __restrict__ C, int ldc,
              int M, int N, int K,
              const float* __restrict__ bias,
              int aZ, int bZ, int cZ)
{
    __shared__ float As[16][68];   // [k][m], padded
    __shared__ float Bs[16][68];   // [k][n]
    A += (size_t)blockIdx.z * aZ;
    B += (size_t)blockIdx.z * bZ;
    C += (size_t)blockIdx.z * cZ;
    const int m0 = blockIdx.y * 64;
    const int n0 = blockIdx.x * 64;
    const int tid = threadIdx.x;
    const int tm = tid >> 4;            // 0..15
    const int tn = tid & 15;            // 0..15
    const int lr = tid >> 2;            // 0..63  (tile row for loads)
    const int lc = (tid & 3) << 2;      // 0,4,8,12 (k-col for loads)

    float acc[4][4] = {};

    for (int k0 = 0; k0 < K; k0 += 16) {
        float4 av = make_float4(0.f, 0.f, 0.f, 0.f);
        float4 bv = make_float4(0.f, 0.f, 0.f, 0.f);
        const int am = m0 + lr;
        if (am < M) av = *(const float4*)(A + (size_t)am * lda + k0 + lc);
        const int bn = n0 + lr;
        if (bn < N) bv = *(const float4*)(B + (size_t)bn * ldb + k0 + lc);
        As[lc + 0][lr] = av.x; As[lc + 1][lr] = av.y;
        As[lc + 2][lr] = av.z; As[lc + 3][lr] = av.w;
        Bs[lc + 0][lr] = bv.x; Bs[lc + 1][lr] = bv.y;
        Bs[lc + 2][lr] = bv.z; Bs[lc + 3][lr] = bv.w;
        __syncthreads();
        #pragma unroll
        for (int k = 0; k < 16; ++k) {
            float a[4], b[4];
            #pragma unroll
            for (int i = 0; i < 4; ++i) a[i] = As[k][tm * 4 + i];
            #pragma unroll
            for (int j = 0; j < 4; ++j) b[j] = Bs[k][tn * 4 + j];
            #pragma unroll
            for (int i = 0; i < 4; ++i)
                #pragma unroll
                for (int j = 0; j < 4; ++j)
                    acc[i][j] += a[i] * b[j];
        }
        __syncthreads();
    }

    #pragma unroll
    for (int i = 0; i < 4; ++i) {
        const int row = m0 + tm * 4 + i;
        if (row >= M) continue;
        #pragma unroll
        for (int j = 0; j < 4; ++j) {
            const int col = n0 + tn * 4 + j;
            if (col < N) {
                float v = acc[i][j];
                if (bias) v += bias[col];
                C[(size_t)row * ldc + col] = v;
            }
        }
    }
}

// ---------------------------------------------------------------------------
// Small helpers
// ---------------------------------------------------------------------------
__device__ __forceinline__ float block_sum_256(float v, float* red)
{
    #pragma unroll
    for (int off = 32; off; off >>= 1) v += __shfl_down(v, off, 64);
    const int lane = threadIdx.x & 63, wid = threadIdx.x >> 6;
    __syncthreads();                    // protect red[] from previous call
    if (lane == 0) red[wid] = v;
    __syncthreads();
    return red[0] + red[1] + red[2] + red[3];
}

__global__ void zero_small(float* p, int n)
{
    int i = blockIdx.x * blockDim.x + threadIdx.x;
    if (i < n) p[i] = 0.f;
}

// key_norm: l2-normalize each 64-wide row of key_mem (896 rows)
__global__ void prep_key_norm(const float* __restrict__ km, float* __restrict__ kn)
{
    const int row = blockIdx.x;
    const int lane = threadIdx.x;      // 64 threads
    float v = km[(size_t)row * HD + lane];
    float s = v * v;
    #pragma unroll
    for (int off = 32; off; off >>= 1) s += __shfl_down(s, off, 64);
    s = __shfl(s, 0, 64);
    const float inv = 1.f / fmaxf(sqrtf(s), 1e-12f);
    kn[(size_t)row * HD + lane] = v * inv;
}

// value_norm (l2 rows of value_mem) + vmT (raw transpose for aud GEMM)
__global__ void prep_value_norm(const float* __restrict__ vm,
                                float* __restrict__ vn, float* __restrict__ vmT)
{
    const int row = blockIdx.x;        // 0..111
    const int tid = threadIdx.x;       // 256
    __shared__ float red[4];
    const float v0 = vm[(size_t)row * DIMC + tid];
    const float v1 = vm[(size_t)row * DIMC + 256 + tid];
    const float tot = block_sum_256(v0 * v0 + v1 * v1, red);
    const float inv = 1.f / fmaxf(sqrtf(tot), 1e-12f);
    vn[(size_t)row * DIMC + tid]        = v0 * inv;
    vn[(size_t)row * DIMC + 256 + tid]  = v1 * inv;
    vmT[(size_t)tid * SLOTS + row]         = v0;
    vmT[(size_t)(256 + tid) * SLOTS + row] = v1;
}

// contrastive = 0.5 * sum |I - vn@vn^T|
__global__ void contrastive_kernel(const float* __restrict__ vn, float* __restrict__ outc)
{
    __shared__ float vni[DIMC];
    __shared__ float red[2];
    const int i = blockIdx.x, tid = threadIdx.x;   // 128 threads
    for (int d = tid; d < DIMC; d += 128) vni[d] = vn[(size_t)i * DIMC + d];
    __syncthreads();
    float t = 0.f;
    if (tid < SLOTS) {
        const float* r = vn + (size_t)tid * DIMC;
        float dot = 0.f;
        for (int d = 0; d < DIMC; ++d) dot += vni[d] * r[d];
        const float delta = (tid == i) ? 1.f : 0.f;
        t = fabsf(delta - dot);
    }
    #pragma unroll
    for (int off = 32; off; off >>= 1) t += __shfl_down(t, off, 64);
    if ((tid & 63) == 0) red[tid >> 6] = t;
    __syncthreads();
    if (tid == 0) atomicAdd(outc, 0.5f * (red[0] + red[1]));
}

// Per-(row,head) inverse l2 norm of eq: hinv[r*8+h] = 1/max(||eq[r,h,:]||,1e-12)
// One wave per row; lane l covers 8 floats; 8-lane subgroup = one head.
__global__ __launch_bounds__(256)
void eq_head_norms(const float* __restrict__ eq, float* __restrict__ hinv)
{
    const int wid  = threadIdx.x >> 6;
    const int lane = threadIdx.x & 63;
    const int r = blockIdx.x * 4 + wid;
    const float4 v0 = *(const float4*)(eq + (size_t)r * DIMC + lane * 8);
    const float4 v1 = *(const float4*)(eq + (size_t)r * DIMC + lane * 8 + 4);
    float s = v0.x * v0.x + v0.y * v0.y + v0.z * v0.z + v0.w * v0.w
            + v1.x * v1.x + v1.y * v1.y + v1.z * v1.z + v1.w * v1.w;
    s += __shfl_down(s, 4, 8);
    s += __shfl_down(s, 2, 8);
    s += __shfl_down(s, 1, 8);
    if ((lane & 7) == 0)
        hinv[(size_t)r * HEADS + (lane >> 3)] = 1.f / fmaxf(sqrtf(s), 1e-12f);
}

// In-place per-head softmax over 112 slots of sim row, scaled by RADIUS*hinv.
// Block = 256 threads = 8 heads x 32 lanes; one row per block.
__global__ __launch_bounds__(256)
void key_softmax(float* __restrict__ sim, const float* __restrict__ hinv)
{
    const int r = blockIdx.x, tid = threadIdx.x;
    const int g = tid >> 5, li = tid & 31;
    const float scale = RADIUSF * hinv[(size_t)r * HEADS + g];
    float* row = sim + (size_t)r * (HEADS * SLOTS) + g * SLOTS;

    float v[4];
    #pragma unroll
    for (int u = 0; u < 4; ++u) {
        const int s = li + u * 32;
        v[u] = (s < SLOTS) ? row[s] * scale : -1e30f;
    }
    float mx = fmaxf(fmaxf(v[0], v[1]), fmaxf(v[2], v[3]));
    #pragma unroll
    for (int off = 16; off; off >>= 1) mx = fmaxf(mx, __shfl_down(mx, off, 32));
    mx = __shfl(mx, 0, 32);
    float e[4]; float sum = 0.f;
    #pragma unroll
    for (int u = 0; u < 4; ++u) {
        const int s = li + u * 32;
        e[u] = (s < SLOTS) ? __expf(v[u] - mx) : 0.f;
        sum += e[u];
    }
    #pragma unroll
    for (int off = 16; off; off >>= 1) sum += __shfl_down(sum, off, 32);
    sum = __shfl(sum, 0, 32);
    const float invs = 1.f / sum;
    #pragma unroll
    for (int u = 0; u < 4; ++u) {
        const int s = li + u * 32;
        if (s < SLOTS) row[s] = e[u] * invs;
    }
}

// vir_pre -> LN(g2,b2) -> +query -> LN(g1,b1) -> out_te
__global__ __launch_bounds__(256)
void vir_te_kernel(const float* __restrict__ vir_pre, const float* __restrict__ query,
                   const float* __restrict__ g1, const float* __restrict__ b1,
                   const float* __restrict__ g2, const float* __restrict__ b2,
                   float* __restrict__ out_te)
{
    const int r = blockIdx.x, tid = threadIdx.x;
    __shared__ float red[4];
    float x0 = vir_pre[(size_t)r * DIMC + tid];
    float x1 = vir_pre[(size_t)r * DIMC + 256 + tid];
    float mu = block_sum_256(x0 + x1, red) * (1.f / DIMC);
    float d0 = x0 - mu, d1 = x1 - mu;
    float var = block_sum_256(d0 * d0 + d1 * d1, red) * (1.f / DIMC);
    float rstd = rsqrtf(var + 1e-5f);
    const float v0 = d0 * rstd * g2[tid] + b2[tid];
    const float v1 = d1 * rstd * g2[tid + 256] + b2[tid + 256];
    const float q0 = query[(size_t)r * DIMC + tid];
    const float q1 = query[(size_t)r * DIMC + 256 + tid];
    float y0 = q0 + v0, y1 = q1 + v1;
    mu = block_sum_256(y0 + y1, red) * (1.f / DIMC);
    d0 = y0 - mu; d1 = y1 - mu;
    var = block_sum_256(d0 * d0 + d1 * d1, red) * (1.f / DIMC);
    rstd = rsqrtf(var + 1e-5f);
    out_te[(size_t)r * DIMC + tid]       = d0 * rstd * g1[tid] + b1[tid];
    out_te[(size_t)r * DIMC + 256 + tid] = d1 * rstd * g1[tid + 256] + b1[tid + 256];
}

// l2-normalize 512-wide rows in place (ev -> evn)
__global__ __launch_bounds__(256)
void l2norm_rows(float* __restrict__ x)
{
    const int r = blockIdx.x, tid = threadIdx.x;
    __shared__ float red[4];
    const float v0 = x[(size_t)r * DIMC + tid];
    const float v1 = x[(size_t)r * DIMC + 256 + tid];
    const float s = block_sum_256(v0 * v0 + v1 * v1, red);
    const float inv = 1.f / fmaxf(sqrtf(s), 1e-12f);
    x[(size_t)r * DIMC + tid]       = v0 * inv;
    x[(size_t)r * DIMC + 256 + tid] = v1 * inv;
}

// softmax(16*x) over 112 slots, in place
__global__ __launch_bounds__(128)
void value_softmax(float* __restrict__ vs)
{
    const int r = blockIdx.x, tid = threadIdx.x;   // 128 threads
    __shared__ float red[2];
    const float v = (tid < SLOTS) ? vs[(size_t)r * SLOTS + tid] * RADIUSF : -1e30f;
    float m = v;
    #pragma unroll
    for (int off = 32; off; off >>= 1) m = fmaxf(m, __shfl_down(m, off, 64));
    if ((tid & 63) == 0) red[tid >> 6] = m;
    __syncthreads();
    m = fmaxf(red[0], red[1]);
    const float e = (tid < SLOTS) ? __expf(v - m) : 0.f;
    __syncthreads();
    float s = e;
    #pragma unroll
    for (int off = 32; off; off >>= 1) s += __shfl_down(s, off, 64);
    if ((tid & 63) == 0) red[tid >> 6] = s;
    __syncthreads();
    s = red[0] + red[1];
    if (tid < SLOTS) vs[(size_t)r * SLOTS + tid] = e / s;
}

// aud: cos/recon, LN(g3,b3), +query, LN(g1,b1) -> out_tr
__global__ __launch_bounds__(256)
void aud_epilogue(const float* __restrict__ aud, const float* __restrict__ value,
                  const float* __restrict__ query,
                  const float* __restrict__ g1, const float* __restrict__ b1,
                  const float* __restrict__ g3, const float* __restrict__ b3,
                  float* __restrict__ out_tr, float* __restrict__ recon)
{
    const int r = blockIdx.x, tid = threadIdx.x;
    __shared__ float red[4];
    const float a0 = aud[(size_t)r * DIMC + tid];
    const float a1 = aud[(size_t)r * DIMC + 256 + tid];
    const float v0 = value[(size_t)r * DIMC + tid];
    const float v1 = value[(size_t)r * DIMC + 256 + tid];
    const float dot = block_sum_256(a0 * v0 + a1 * v1, red);
    const float na  = block_sum_256(a0 * a0 + a1 * a1, red);
    const float nv  = block_sum_256(v0 * v0 + v1 * v1, red);
    if (tid == 0) {
        const float cosv = dot / fmaxf(sqrtf(na) * sqrtf(nv), 1e-8f);
        atomicAdd(&recon[r >> 9], fabsf(1.f - cosv));
    }
    float mu = block_sum_256(a0 + a1, red) * (1.f / DIMC);
    float d0 = a0 - mu, d1 = a1 - mu;
    float var = block_sum_256(d0 * d0 + d1 * d1, red) * (1.f / DIMC);
    float rstd = rsqrtf(var + 1e-5f);
    const float w0 = d0 * rstd * g3[tid] + b3[tid];
    const float w1 = d1 * rstd * g3[tid + 256] + b3[tid + 256];
    const float q0 = query[(size_t)r * DIMC + tid];
    const float q1 = query[(size_t)r * DIMC + 256 + tid];
    float y0 = q0 + w0, y1 = q1 + w1;
    mu = block_sum_256(y0 + y1, red) * (1.f / DIMC);
    d0 = y0 - mu; d1 = y1 - mu;
    var = block_sum_256(d0 * d0 + d1 * d1, red) * (1.f / DIMC);
    rstd = rsqrtf(var + 1e-5f);
    out_tr[(size_t)r * DIMC + tid]       = d0 * rstd * g1[tid] + b1[tid];
    out_tr[(size_t)r * DIMC + 256 + tid] = d1 * rstd * g1[tid + 256] + b1[tid + 256];
}

// ---------------------------------------------------------------------------
// Launch
// ---------------------------------------------------------------------------
extern "C" void kernel_launch(void* const* d_in, const int* in_sizes, int n_in,
                              void* d_out, int out_size, void* d_ws, size_t ws_size,
                              hipStream_t stream)
{
    const float* query = (const float*)d_in[0];
    const float* value = (const float*)d_in[1];
    const float* keym  = (const float*)d_in[2];
    const float* vmem  = (const float*)d_in[3];
    const float* Wq    = (const float*)d_in[4];
    const float* bq    = (const float*)d_in[5];
    const float* Wv    = (const float*)d_in[6];
    const float* bv    = (const float*)d_in[7];
    const float* Wl    = (const float*)d_in[8];
    const float* bl    = (const float*)d_in[9];
    const float* g1    = (const float*)d_in[10];
    const float* b1    = (const float*)d_in[11];
    const float* g2    = (const float*)d_in[12];
    const float* b2    = (const float*)d_in[13];
    const float* g3    = (const float*)d_in[14];
    const float* b3    = (const float*)d_in[15];

    float* out    = (float*)d_out;
    float* out_te = out;                       // 16384*512
    float* out_tr = out + 8388608;             // 16384*512
    float* out_rc = out + 16777216;            // 32 recon + 1 contrastive

    // Workspace layout (floats). Total ~136 MB.
    float* ws = (float*)d_ws;
    float* w_kn   = ws + 0;         //   896*64   = 57344
    float* w_vn   = ws + 57344;     //   112*512  = 57344
    float* w_vmT  = ws + 114688;    //   512*112  = 57344
    float* w_W2T  = ws + 172032;    //   512*896  = 458752
    float* w_hinv = ws + 630784;    // 16384*8    = 131072
    float* w_eq   = ws + 761856;    // 16384*512  = 8388608 (reused as vir_pre)
    float* w_kadd = ws + 9150464;   // 16384*896  = 14680064 (sims -> softmax in place)
    float* w_ev   = ws + 23830528;  // 16384*512  = 8388608 (reused as aud)
    float* w_vs   = ws + 32219136;  // 16384*112  = 1835008

    // 0) zero recon+contrastive (d_out is poisoned before every call)
    zero_small<<<1, 64, 0, stream>>>(out_rc, 33);

    // 1) input-only precomputes
    prep_key_norm<<<896, 64, 0, stream>>>(keym, w_kn);
    prep_value_norm<<<112, 256, 0, stream>>>(vmem, w_vn, w_vmT);
    contrastive_kernel<<<112, 128, 0, stream>>>(w_vn, out_rc + 32);
    // W2T[o][h*112+s] = sum_d vm[s][d] * Wl[o][h*512+d]   (8 heads via grid.z)
    gemm_abt<<<dim3(2, 8, 8), 256, 0, stream>>>(
        Wl, 4096, vmem, DIMC, w_W2T, HEADS * SLOTS,
        DIMC, SLOTS, DIMC, nullptr, DIMC, 0, SLOTS);

    // 2) key addressing path
    gemm_abt<<<dim3(8, 256, 1), 256, 0, stream>>>(
        query, DIMC, Wq, DIMC, w_eq, DIMC,
        NROWS, DIMC, DIMC, bq, 0, 0, 0);
    // per-(row,head) inverse norms of eq
    eq_head_norms<<<NROWS / 4, 256, 0, stream>>>(w_eq, w_hinv);
    // sims: per head z, eq[:,64z:64z+64] @ kn_z^T  -> w_kadd[r][z*112+s]
    gemm_abt<<<dim3(2, 256, 8), 256, 0, stream>>>(
        w_eq, DIMC, w_kn, HD, w_kadd, HEADS * SLOTS,
        NROWS, SLOTS, HD, nullptr, HD, SLOTS * HD, SLOTS);
    // scale by RADIUS*hinv + per-head softmax, in place
    key_softmax<<<NROWS, 256, 0, stream>>>(w_kadd, w_hinv);
    gemm_abt<<<dim3(8, 256, 1), 256, 0, stream>>>(            // vir_pre into eq buffer
        w_kadd, HEADS * SLOTS, w_W2T, HEADS * SLOTS, w_eq, DIMC,
        NROWS, DIMC, HEADS * SLOTS, bl, 0, 0, 0);
    vir_te_kernel<<<NROWS, 256, 0, stream>>>(w_eq, query, g1, b1, g2, b2, out_te);

    // 3) value addressing path
    gemm_abt<<<dim3(8, 256, 1), 256, 0, stream>>>(
        value, DIMC, Wv, DIMC, w_ev, DIMC,
        NROWS, DIMC, DIMC, bv, 0, 0, 0);
    l2norm_rows<<<NROWS, 256, 0, stream>>>(w_ev);
    gemm_abt<<<dim3(2, 256, 1), 256, 0, stream>>>(
        w_ev, DIMC, w_vn, DIMC, w_vs, SLOTS,
        NROWS, SLOTS, DIMC, nullptr, 0, 0, 0);
    value_softmax<<<NROWS, 128, 0, stream>>>(w_vs);
    gemm_abt<<<dim3(8, 256, 1), 256, 0, stream>>>(            // aud into ev buffer
        w_vs, SLOTS, w_vmT, SLOTS, w_ev, DIMC,
        NROWS, DIMC, SLOTS, nullptr, 0, 0, 0);
    aud_epilogue<<<NROWS, 256, 0, stream>>>(
        w_ev, value, query, g1, b1, g3, b3, out_tr, out_rc);
}

// Round 4
// 640.923 us; speedup vs baseline: 2.3382x; 1.5638x over previous
//
#include <hip/hip_runtime.h>
#include <math.h>

// Problem constants
#define DIMC   512
#define HEADS  8
#define SLOTS  112
#define HD     64          // DIMC/HEADS
#define NROWS  16384       // B*S = 32*512
#define RADIUSF 16.0f

typedef short short8 __attribute__((ext_vector_type(8)));
typedef float f32x4  __attribute__((ext_vector_type(4)));

__device__ __forceinline__ unsigned short f2bf(float f)
{
    unsigned u = __float_as_uint(f);
    unsigned r = (u + 0x7FFFu + ((u >> 16) & 1u)) >> 16;   // RNE
    return (unsigned short)r;
}

// ---------------------------------------------------------------------------
// bf16 MFMA GEMM: C(MxN fp32) = A(MxK bf16) @ B(NxK bf16)^T (+ bias[col])
// 128x128 tile, BK=32, 256 threads = 4 waves, each wave a 64x64 quadrant
// (4x4 frags of 16x16x32). M,N multiples of 128; K multiple of 32.
// lda/ldb are element strides (shorts); ldc floats.
// ---------------------------------------------------------------------------
__global__ __launch_bounds__(256)
void gemm_bf16(const short* __restrict__ A, int lda,
               const short* __restrict__ B, int ldb,
               float* __restrict__ C, int ldc,
               int K, const float* __restrict__ bias)
{
    __shared__ short As[128 * 32];
    __shared__ short Bs[128 * 32];
    const int tid  = threadIdx.x;
    const int wave = tid >> 6;
    const int lane = tid & 63;
    const int m0 = blockIdx.y * 128;
    const int n0 = blockIdx.x * 128;
    const int wm = (wave >> 1) * 64;     // wave quadrant
    const int wn = (wave & 1) * 64;

    const int srow = tid >> 2;           // staging: rows 0..63 (+64)
    const int schk = (tid & 3) * 8;      // 16B chunk within 32-elem row

    const int fr = lane & 15;            // frag row (m or n within 16)
    const int fq = (lane >> 4) * 8;      // frag k-offset

    f32x4 acc[4][4] = {};

    const short* Ag = A + (size_t)(m0 + srow) * lda + schk;
    const short* Bg = B + (size_t)(n0 + srow) * ldb + schk;

    for (int k0 = 0; k0 < K; k0 += 32) {
        *(short8*)&As[srow * 32 + schk]        = *(const short8*)(Ag);
        *(short8*)&As[(srow + 64) * 32 + schk] = *(const short8*)(Ag + (size_t)64 * lda);
        *(short8*)&Bs[srow * 32 + schk]        = *(const short8*)(Bg);
        *(short8*)&Bs[(srow + 64) * 32 + schk] = *(const short8*)(Bg + (size_t)64 * ldb);
        Ag += 32; Bg += 32;
        __syncthreads();
        short8 af[4], bf[4];
        #pragma unroll
        for (int i = 0; i < 4; ++i)
            af[i] = *(const short8*)&As[(wm + i * 16 + fr) * 32 + fq];
        #pragma unroll
        for (int j = 0; j < 4; ++j)
            bf[j] = *(const short8*)&Bs[(wn + j * 16 + fr) * 32 + fq];
        #pragma unroll
        for (int i = 0; i < 4; ++i)
            #pragma unroll
            for (int j = 0; j < 4; ++j)
                acc[i][j] = __builtin_amdgcn_mfma_f32_16x16x32_bf16(
                    af[i], bf[j], acc[i][j], 0, 0, 0);
        __syncthreads();
    }

    // C/D layout: col = lane&15, row = (lane>>4)*4 + reg
    const int cr = (lane >> 4) * 4;
    const int cc = lane & 15;
    #pragma unroll
    for (int i = 0; i < 4; ++i) {
        const int grow = m0 + wm + i * 16 + cr;
        #pragma unroll
        for (int j = 0; j < 4; ++j) {
            const int gcol = n0 + wn + j * 16 + cc;
            const float bb = bias ? bias[gcol] : 0.f;
            float* cp = C + (size_t)grow * ldc + gcol;
            #pragma unroll
            for (int r = 0; r < 4; ++r)
                cp[(size_t)r * ldc] = acc[i][j][r] + bb;
        }
    }
}

// ---------------------------------------------------------------------------
// Generic tiled fp32 GEMM: C(MxN) = A(MxK) @ B(NxK)^T (+ bias[col])
// (kept for the small/precision-critical GEMMs)
// ---------------------------------------------------------------------------
__global__ __launch_bounds__(256)
void gemm_abt(const float* __restrict__ A, int lda,
              const float* __restrict__ B, int ldb,
              float* __restrict__ C, int ldc,
              int M, int N, int K,
              const float* __restrict__ bias,
              int aZ, int bZ, int cZ)
{
    __shared__ float As[16][68];
    __shared__ float Bs[16][68];
    A += (size_t)blockIdx.z * aZ;
    B += (size_t)blockIdx.z * bZ;
    C += (size_t)blockIdx.z * cZ;
    const int m0 = blockIdx.y * 64;
    const int n0 = blockIdx.x * 64;
    const int tid = threadIdx.x;
    const int tm = tid >> 4;
    const int tn = tid & 15;
    const int lr = tid >> 2;
    const int lc = (tid & 3) << 2;

    float acc[4][4] = {};

    for (int k0 = 0; k0 < K; k0 += 16) {
        float4 av = make_float4(0.f, 0.f, 0.f, 0.f);
        float4 bv = make_float4(0.f, 0.f, 0.f, 0.f);
        const int am = m0 + lr;
        if (am < M) av = *(const float4*)(A + (size_t)am * lda + k0 + lc);
        const int bn = n0 + lr;
        if (bn < N) bv = *(const float4*)(B + (size_t)bn * ldb + k0 + lc);
        As[lc + 0][lr] = av.x; As[lc + 1][lr] = av.y;
        As[lc + 2][lr] = av.z; As[lc + 3][lr] = av.w;
        Bs[lc + 0][lr] = bv.x; Bs[lc + 1][lr] = bv.y;
        Bs[lc + 2][lr] = bv.z; Bs[lc + 3][lr] = bv.w;
        __syncthreads();
        #pragma unroll
        for (int k = 0; k < 16; ++k) {
            float a[4], b[4];
            #pragma unroll
            for (int i = 0; i < 4; ++i) a[i] = As[k][tm * 4 + i];
            #pragma unroll
            for (int j = 0; j < 4; ++j) b[j] = Bs[k][tn * 4 + j];
            #pragma unroll
            for (int i = 0; i < 4; ++i)
                #pragma unroll
                for (int j = 0; j < 4; ++j)
                    acc[i][j] += a[i] * b[j];
        }
        __syncthreads();
    }

    #pragma unroll
    for (int i = 0; i < 4; ++i) {
        const int row = m0 + tm * 4 + i;
        if (row >= M) continue;
        #pragma unroll
        for (int j = 0; j < 4; ++j) {
            const int col = n0 + tn * 4 + j;
            if (col < N) {
                float v = acc[i][j];
                if (bias) v += bias[col];
                C[(size_t)row * ldc + col] = v;
            }
        }
    }
}

// ---------------------------------------------------------------------------
// Small helpers
// ---------------------------------------------------------------------------
__device__ __forceinline__ float block_sum_256(float v, float* red)
{
    #pragma unroll
    for (int off = 32; off; off >>= 1) v += __shfl_down(v, off, 64);
    const int lane = threadIdx.x & 63, wid = threadIdx.x >> 6;
    __syncthreads();
    if (lane == 0) red[wid] = v;
    __syncthreads();
    return red[0] + red[1] + red[2] + red[3];
}

__global__ void zero_small(float* p, int n)
{
    int i = blockIdx.x * blockDim.x + threadIdx.x;
    if (i < n) p[i] = 0.f;
}

// fp32 -> bf16 (RNE), n multiple of 4
__global__ void f32_to_bf16(const float* __restrict__ src,
                            unsigned short* __restrict__ dst, int n)
{
    int i = (blockIdx.x * blockDim.x + threadIdx.x) * 4;
    if (i >= n) return;
    float4 v = *(const float4*)(src + i);
    ushort4 o;
    o.x = f2bf(v.x); o.y = f2bf(v.y); o.z = f2bf(v.z); o.w = f2bf(v.w);
    *(ushort4*)(dst + i) = o;
}

__global__ void prep_key_norm(const float* __restrict__ km, float* __restrict__ kn)
{
    const int row = blockIdx.x;
    const int lane = threadIdx.x;      // 64 threads
    float v = km[(size_t)row * HD + lane];
    float s = v * v;
    #pragma unroll
    for (int off = 32; off; off >>= 1) s += __shfl_down(s, off, 64);
    s = __shfl(s, 0, 64);
    const float inv = 1.f / fmaxf(sqrtf(s), 1e-12f);
    kn[(size_t)row * HD + lane] = v * inv;
}

__global__ void prep_value_norm(const float* __restrict__ vm,
                                float* __restrict__ vn, float* __restrict__ vmT)
{
    const int row = blockIdx.x;        // 0..111
    const int tid = threadIdx.x;       // 256
    __shared__ float red[4];
    const float v0 = vm[(size_t)row * DIMC + tid];
    const float v1 = vm[(size_t)row * DIMC + 256 + tid];
    const float tot = block_sum_256(v0 * v0 + v1 * v1, red);
    const float inv = 1.f / fmaxf(sqrtf(tot), 1e-12f);
    vn[(size_t)row * DIMC + tid]        = v0 * inv;
    vn[(size_t)row * DIMC + 256 + tid]  = v1 * inv;
    vmT[(size_t)tid * SLOTS + row]         = v0;
    vmT[(size_t)(256 + tid) * SLOTS + row] = v1;
}

__global__ void contrastive_kernel(const float* __restrict__ vn, float* __restrict__ outc)
{
    __shared__ float vni[DIMC];
    __shared__ float red[2];
    const int i = blockIdx.x, tid = threadIdx.x;   // 128 threads
    for (int d = tid; d < DIMC; d += 128) vni[d] = vn[(size_t)i * DIMC + d];
    __syncthreads();
    float t = 0.f;
    if (tid < SLOTS) {
        const float* r = vn + (size_t)tid * DIMC;
        float dot = 0.f;
        for (int d = 0; d < DIMC; ++d) dot += vni[d] * r[d];
        const float delta = (tid == i) ? 1.f : 0.f;
        t = fabsf(delta - dot);
    }
    #pragma unroll
    for (int off = 32; off; off >>= 1) t += __shfl_down(t, off, 64);
    if ((tid & 63) == 0) red[tid >> 6] = t;
    __syncthreads();
    if (tid == 0) atomicAdd(outc, 0.5f * (red[0] + red[1]));
}

// Per-(row,head) inverse l2 norm of eq
__global__ __launch_bounds__(256)
void eq_head_norms(const float* __restrict__ eq, float* __restrict__ hinv)
{
    const int wid  = threadIdx.x >> 6;
    const int lane = threadIdx.x & 63;
    const int r = blockIdx.x * 4 + wid;
    const float4 v0 = *(const float4*)(eq + (size_t)r * DIMC + lane * 8);
    const float4 v1 = *(const float4*)(eq + (size_t)r * DIMC + lane * 8 + 4);
    float s = v0.x * v0.x + v0.y * v0.y + v0.z * v0.z + v0.w * v0.w
            + v1.x * v1.x + v1.y * v1.y + v1.z * v1.z + v1.w * v1.w;
    s += __shfl_down(s, 4, 8);
    s += __shfl_down(s, 2, 8);
    s += __shfl_down(s, 1, 8);
    if ((lane & 7) == 0)
        hinv[(size_t)r * HEADS + (lane >> 3)] = 1.f / fmaxf(sqrtf(s), 1e-12f);
}

// Per-head softmax over 112 slots of sim row (scaled by RADIUS*hinv),
// output written as bf16 IN PLACE over the same row's storage:
// fp32 row r at sim + r*896 (floats); bf16 row r at kadd + r*1792 (shorts),
// i.e. the first 448 floats of the same row slot. Per-row block, barrier
// between reads and writes.
__global__ __launch_bounds__(256)
void key_softmax(const float* __restrict__ sim, unsigned short* __restrict__ kadd,
                 const float* __restrict__ hinv)
{
    const int r = blockIdx.x, tid = threadIdx.x;
    const int g = tid >> 5, li = tid & 31;
    const float scale = RADIUSF * hinv[(size_t)r * HEADS + g];
    const float* row = sim + (size_t)r * (HEADS * SLOTS) + g * SLOTS;
    unsigned short* orow = kadd + (size_t)r * (2 * HEADS * SLOTS) + g * SLOTS;

    float v[4];
    #pragma unroll
    for (int u = 0; u < 4; ++u) {
        const int s = li + u * 32;
        v[u] = (s < SLOTS) ? row[s] * scale : -1e30f;
    }
    __syncthreads();   // all reads of this row done before any bf16 write
    float mx = fmaxf(fmaxf(v[0], v[1]), fmaxf(v[2], v[3]));
    #pragma unroll
    for (int off = 16; off; off >>= 1) mx = fmaxf(mx, __shfl_down(mx, off, 32));
    mx = __shfl(mx, 0, 32);
    float e[4]; float sum = 0.f;
    #pragma unroll
    for (int u = 0; u < 4; ++u) {
        const int s = li + u * 32;
        e[u] = (s < SLOTS) ? __expf(v[u] - mx) : 0.f;
        sum += e[u];
    }
    #pragma unroll
    for (int off = 16; off; off >>= 1) sum += __shfl_down(sum, off, 32);
    sum = __shfl(sum, 0, 32);
    const float invs = 1.f / sum;
    #pragma unroll
    for (int u = 0; u < 4; ++u) {
        const int s = li + u * 32;
        if (s < SLOTS) orow[s] = f2bf(e[u] * invs);
    }
}

__global__ __launch_bounds__(256)
void vir_te_kernel(const float* __restrict__ vir_pre, const float* __restrict__ query,
                   const float* __restrict__ g1, const float* __restrict__ b1,
                   const float* __restrict__ g2, const float* __restrict__ b2,
                   float* __restrict__ out_te)
{
    const int r = blockIdx.x, tid = threadIdx.x;
    __shared__ float red[4];
    float x0 = vir_pre[(size_t)r * DIMC + tid];
    float x1 = vir_pre[(size_t)r * DIMC + 256 + tid];
    float mu = block_sum_256(x0 + x1, red) * (1.f / DIMC);
    float d0 = x0 - mu, d1 = x1 - mu;
    float var = block_sum_256(d0 * d0 + d1 * d1, red) * (1.f / DIMC);
    float rstd = rsqrtf(var + 1e-5f);
    const float v0 = d0 * rstd * g2[tid] + b2[tid];
    const float v1 = d1 * rstd * g2[tid + 256] + b2[tid + 256];
    const float q0 = query[(size_t)r * DIMC + tid];
    const float q1 = query[(size_t)r * DIMC + 256 + tid];
    float y0 = q0 + v0, y1 = q1 + v1;
    mu = block_sum_256(y0 + y1, red) * (1.f / DIMC);
    d0 = y0 - mu; d1 = y1 - mu;
    var = block_sum_256(d0 * d0 + d1 * d1, red) * (1.f / DIMC);
    rstd = rsqrtf(var + 1e-5f);
    out_te[(size_t)r * DIMC + tid]       = d0 * rstd * g1[tid] + b1[tid];
    out_te[(size_t)r * DIMC + 256 + tid] = d1 * rstd * g1[tid + 256] + b1[tid + 256];
}

__global__ __launch_bounds__(256)
void l2norm_rows(float* __restrict__ x)
{
    const int r = blockIdx.x, tid = threadIdx.x;
    __shared__ float red[4];
    const float v0 = x[(size_t)r * DIMC + tid];
    const float v1 = x[(size_t)r * DIMC + 256 + tid];
    const float s = block_sum_256(v0 * v0 + v1 * v1, red);
    const float inv = 1.f / fmaxf(sqrtf(s), 1e-12f);
    x[(size_t)r * DIMC + tid]       = v0 * inv;
    x[(size_t)r * DIMC + 256 + tid] = v1 * inv;
}

__global__ __launch_bounds__(128)
void value_softmax(float* __restrict__ vs)
{
    const int r = blockIdx.x, tid = threadIdx.x;   // 128 threads
    __shared__ float red[2];
    const float v = (tid < SLOTS) ? vs[(size_t)r * SLOTS + tid] * RADIUSF : -1e30f;
    float m = v;
    #pragma unroll
    for (int off = 32; off; off >>= 1) m = fmaxf(m, __shfl_down(m, off, 64));
    if ((tid & 63) == 0) red[tid >> 6] = m;
    __syncthreads();
    m = fmaxf(red[0], red[1]);
    const float e = (tid < SLOTS) ? __expf(v - m) : 0.f;
    __syncthreads();
    float s = e;
    #pragma unroll
    for (int off = 32; off; off >>= 1) s += __shfl_down(s, off, 64);
    if ((tid & 63) == 0) red[tid >> 6] = s;
    __syncthreads();
    s = red[0] + red[1];
    if (tid < SLOTS) vs[(size_t)r * SLOTS + tid] = e / s;
}

__global__ __launch_bounds__(256)
void aud_epilogue(const float* __restrict__ aud, const float* __restrict__ value,
                  const float* __restrict__ query,
                  const float* __restrict__ g1, const float* __restrict__ b1,
                  const float* __restrict__ g3, const float* __restrict__ b3,
                  float* __restrict__ out_tr, float* __restrict__ recon)
{
    const int r = blockIdx.x, tid = threadIdx.x;
    __shared__ float red[4];
    const float a0 = aud[(size_t)r * DIMC + tid];
    const float a1 = aud[(size_t)r * DIMC + 256 + tid];
    const float v0 = value[(size_t)r * DIMC + tid];
    const float v1 = value[(size_t)r * DIMC + 256 + tid];
    const float dot = block_sum_256(a0 * v0 + a1 * v1, red);
    const float na  = block_sum_256(a0 * a0 + a1 * a1, red);
    const float nv  = block_sum_256(v0 * v0 + v1 * v1, red);
    if (tid == 0) {
        const float cosv = dot / fmaxf(sqrtf(na) * sqrtf(nv), 1e-8f);
        atomicAdd(&recon[r >> 9], fabsf(1.f - cosv));
    }
    float mu = block_sum_256(a0 + a1, red) * (1.f / DIMC);
    float d0 = a0 - mu, d1 = a1 - mu;
    float var = block_sum_256(d0 * d0 + d1 * d1, red) * (1.f / DIMC);
    float rstd = rsqrtf(var + 1e-5f);
    const float w0 = d0 * rstd * g3[tid] + b3[tid];
    const float w1 = d1 * rstd * g3[tid + 256] + b3[tid + 256];
    const float q0 = query[(size_t)r * DIMC + tid];
    const float q1 = query[(size_t)r * DIMC + 256 + tid];
    float y0 = q0 + w0, y1 = q1 + w1;
    mu = block_sum_256(y0 + y1, red) * (1.f / DIMC);
    d0 = y0 - mu; d1 = y1 - mu;
    var = block_sum_256(d0 * d0 + d1 * d1, red) * (1.f / DIMC);
    rstd = rsqrtf(var + 1e-5f);
    out_tr[(size_t)r * DIMC + tid]       = d0 * rstd * g1[tid] + b1[tid];
    out_tr[(size_t)r * DIMC + 256 + tid] = d1 * rstd * g1[tid + 256] + b1[tid + 256];
}

// ---------------------------------------------------------------------------
// Launch
// ---------------------------------------------------------------------------
extern "C" void kernel_launch(void* const* d_in, const int* in_sizes, int n_in,
                              void* d_out, int out_size, void* d_ws, size_t ws_size,
                              hipStream_t stream)
{
    const float* query = (const float*)d_in[0];
    const float* value = (const float*)d_in[1];
    const float* keym  = (const float*)d_in[2];
    const float* vmem  = (const float*)d_in[3];
    const float* Wq    = (const float*)d_in[4];
    const float* bq    = (const float*)d_in[5];
    const float* Wv    = (const float*)d_in[6];
    const float* bv    = (const float*)d_in[7];
    const float* Wl    = (const float*)d_in[8];
    const float* bl    = (const float*)d_in[9];
    const float* g1    = (const float*)d_in[10];
    const float* b1    = (const float*)d_in[11];
    const float* g2    = (const float*)d_in[12];
    const float* b2    = (const float*)d_in[13];
    const float* g3    = (const float*)d_in[14];
    const float* b3    = (const float*)d_in[15];

    float* out    = (float*)d_out;
    float* out_te = out;
    float* out_tr = out + 8388608;
    float* out_rc = out + 16777216;    // 32 recon + 1 contrastive

    // Workspace layout (float offsets). Total 34,054,144 floats = 136.2 MB.
    float* ws = (float*)d_ws;
    float* w_kn   = ws + 0;         //   896*64
    float* w_vn   = ws + 57344;     //   112*512
    float* w_vmT  = ws + 114688;    //   512*112
    float* w_W2T  = ws + 172032;    //   512*896 fp32
    float* w_hinv = ws + 630784;    // 16384*8
    float* w_eq   = ws + 761856;    // 16384*512 fp32 (eq -> vir_pre)
    float* w_sims = ws + 9150464;   // 16384*896 fp32 [9150464, 23830528)
    float* w_ev   = ws + 23830528;  // 16384*512 fp32 [23830528, 32219136) (ev -> aud)
    float* w_vs   = ws + 32219136;  // 16384*112 fp32

    // bf16 staging aliases — lifetimes verified against stream order:
    //  * qbf/wqbf/w2tbf live in the w_ev region: all three are fully consumed
    //    (eq GEMM, vir GEMM) BEFORE the ev GEMM writes w_ev.
    unsigned short* w_qbf   = (unsigned short*)(ws + 23830528); // 16384*512 bf16 -> [23830528,28024832)
    unsigned short* w_wqbf  = (unsigned short*)(ws + 28024832); //   512*512 bf16 -> [28024832,28155904)
    unsigned short* w_w2tbf = (unsigned short*)(ws + 28155904); //   512*896 bf16 -> [28155904,28385280)
    //  * kadd bf16 in place over sims rows (row r = first 448 floats of slot r)
    unsigned short* w_kadd  = (unsigned short*)(ws + 9150464);  // rows stride 1792 shorts
    //  * vbf/wvbf live at the sims base: whole sims/kadd region is dead after
    //    the vir GEMM, which precedes these conversions.
    unsigned short* w_vbf   = (unsigned short*)(ws + 9150464);  // 16384*512 bf16 -> [9150464,13344768)
    unsigned short* w_wvbf  = (unsigned short*)(ws + 13344768); //   512*512 bf16 -> [13344768,13475840)

    // 0) zero recon+contrastive
    zero_small<<<1, 64, 0, stream>>>(out_rc, 33);

    // 1) input-only precomputes
    prep_key_norm<<<896, 64, 0, stream>>>(keym, w_kn);
    prep_value_norm<<<112, 256, 0, stream>>>(vmem, w_vn, w_vmT);
    contrastive_kernel<<<112, 128, 0, stream>>>(w_vn, out_rc + 32);
    gemm_abt<<<dim3(2, 8, 8), 256, 0, stream>>>(              // W2T fp32
        Wl, 4096, vmem, DIMC, w_W2T, HEADS * SLOTS,
        DIMC, SLOTS, DIMC, nullptr, DIMC, 0, SLOTS);
    f32_to_bf16<<<448, 256, 0, stream>>>(w_W2T, w_w2tbf, DIMC * HEADS * SLOTS);

    // 2) key addressing path
    f32_to_bf16<<<8192, 256, 0, stream>>>(query, w_qbf, NROWS * DIMC);
    f32_to_bf16<<<256, 256, 0, stream>>>(Wq, w_wqbf, DIMC * DIMC);
    gemm_bf16<<<dim3(4, 128), 256, 0, stream>>>(              // eq = q@Wq^T + bq
        (const short*)w_qbf, DIMC, (const short*)w_wqbf, DIMC,
        w_eq, DIMC, DIMC, bq);
    eq_head_norms<<<NROWS / 4, 256, 0, stream>>>(w_eq, w_hinv);
    gemm_abt<<<dim3(2, 256, 8), 256, 0, stream>>>(            // sims (fp32)
        w_eq, DIMC, w_kn, HD, w_sims, HEADS * SLOTS,
        NROWS, SLOTS, HD, nullptr, HD, SLOTS * HD, SLOTS);
    key_softmax<<<NROWS, 256, 0, stream>>>(w_sims, w_kadd, w_hinv);
    gemm_bf16<<<dim3(4, 128), 256, 0, stream>>>(              // vir_pre = kadd@W2T^T + bl
        (const short*)w_kadd, 2 * HEADS * SLOTS, (const short*)w_w2tbf, HEADS * SLOTS,
        w_eq, DIMC, HEADS * SLOTS, bl);
    vir_te_kernel<<<NROWS, 256, 0, stream>>>(w_eq, query, g1, b1, g2, b2, out_te);

    // 3) value addressing path (vbf/wvbf clobber dead sims/kadd region)
    f32_to_bf16<<<8192, 256, 0, stream>>>(value, w_vbf, NROWS * DIMC);
    f32_to_bf16<<<256, 256, 0, stream>>>(Wv, w_wvbf, DIMC * DIMC);
    gemm_bf16<<<dim3(4, 128), 256, 0, stream>>>(              // ev = v@Wv^T + bv
        (const short*)w_vbf, DIMC, (const short*)w_wvbf, DIMC,
        w_ev, DIMC, DIMC, bv);
    l2norm_rows<<<NROWS, 256, 0, stream>>>(w_ev);
    gemm_abt<<<dim3(2, 256, 1), 256, 0, stream>>>(            // value_sim (fp32)
        w_ev, DIMC, w_vn, DIMC, w_vs, SLOTS,
        NROWS, SLOTS, DIMC, nullptr, 0, 0, 0);
    value_softmax<<<NROWS, 128, 0, stream>>>(w_vs);
    gemm_abt<<<dim3(8, 256, 1), 256, 0, stream>>>(            // aud (fp32)
        w_vs, SLOTS, w_vmT, SLOTS, w_ev, DIMC,
        NROWS, DIMC, SLOTS, nullptr, 0, 0, 0);
    aud_epilogue<<<NROWS, 256, 0, stream>>>(
        w_ev, value, query, g1, b1, g3, b3, out_tr, out_rc);
}

// Round 5
// 496.703 us; speedup vs baseline: 3.0172x; 1.2904x over previous
//
#include <hip/hip_runtime.h>
#include <math.h>

// Problem constants
#define DIMC   512
#define HEADS  8
#define SLOTS  112
#define HD     64          // DIMC/HEADS
#define NROWS  16384       // B*S = 32*512
#define RADIUSF 16.0f

typedef short short8 __attribute__((ext_vector_type(8)));
typedef float f32x4  __attribute__((ext_vector_type(4)));

__device__ __forceinline__ unsigned short f2bf(float f)
{
    unsigned u = __float_as_uint(f);
    unsigned r = (u + 0x7FFFu + ((u >> 16) & 1u)) >> 16;   // RNE
    return (unsigned short)r;
}

// Fused wave-wide (64-lane) reductions with ILP; results broadcast to all lanes.
__device__ __forceinline__ void wred2(float& a, float& b)
{
    #pragma unroll
    for (int off = 32; off; off >>= 1) {
        a += __shfl_down(a, off, 64);
        b += __shfl_down(b, off, 64);
    }
    a = __shfl(a, 0, 64);
    b = __shfl(b, 0, 64);
}

__device__ __forceinline__ void wred4(float& a, float& b, float& c, float& d)
{
    #pragma unroll
    for (int off = 32; off; off >>= 1) {
        a += __shfl_down(a, off, 64);
        b += __shfl_down(b, off, 64);
        c += __shfl_down(c, off, 64);
        d += __shfl_down(d, off, 64);
    }
    a = __shfl(a, 0, 64);
    b = __shfl(b, 0, 64);
    c = __shfl(c, 0, 64);
    d = __shfl(d, 0, 64);
}

// ---------------------------------------------------------------------------
// bf16 MFMA GEMM: C(MxN fp32) = A(MxK bf16) @ B(NxK bf16)^T (+ bias[col])
// 128x128 tile, BK=32, 256 threads = 4 waves, each wave a 64x64 quadrant.
// ---------------------------------------------------------------------------
__global__ __launch_bounds__(256)
void gemm_bf16(const short* __restrict__ A, int lda,
               const short* __restrict__ B, int ldb,
               float* __restrict__ C, int ldc,
               int K, const float* __restrict__ bias)
{
    __shared__ short As[128 * 32];
    __shared__ short Bs[128 * 32];
    const int tid  = threadIdx.x;
    const int wave = tid >> 6;
    const int lane = tid & 63;
    const int m0 = blockIdx.y * 128;
    const int n0 = blockIdx.x * 128;
    const int wm = (wave >> 1) * 64;
    const int wn = (wave & 1) * 64;

    const int srow = tid >> 2;
    const int schk = (tid & 3) * 8;

    const int fr = lane & 15;
    const int fq = (lane >> 4) * 8;

    f32x4 acc[4][4] = {};

    const short* Ag = A + (size_t)(m0 + srow) * lda + schk;
    const short* Bg = B + (size_t)(n0 + srow) * ldb + schk;

    for (int k0 = 0; k0 < K; k0 += 32) {
        *(short8*)&As[srow * 32 + schk]        = *(const short8*)(Ag);
        *(short8*)&As[(srow + 64) * 32 + schk] = *(const short8*)(Ag + (size_t)64 * lda);
        *(short8*)&Bs[srow * 32 + schk]        = *(const short8*)(Bg);
        *(short8*)&Bs[(srow + 64) * 32 + schk] = *(const short8*)(Bg + (size_t)64 * ldb);
        Ag += 32; Bg += 32;
        __syncthreads();
        short8 af[4], bf[4];
        #pragma unroll
        for (int i = 0; i < 4; ++i)
            af[i] = *(const short8*)&As[(wm + i * 16 + fr) * 32 + fq];
        #pragma unroll
        for (int j = 0; j < 4; ++j)
            bf[j] = *(const short8*)&Bs[(wn + j * 16 + fr) * 32 + fq];
        #pragma unroll
        for (int i = 0; i < 4; ++i)
            #pragma unroll
            for (int j = 0; j < 4; ++j)
                acc[i][j] = __builtin_amdgcn_mfma_f32_16x16x32_bf16(
                    af[i], bf[j], acc[i][j], 0, 0, 0);
        __syncthreads();
    }

    const int cr = (lane >> 4) * 4;
    const int cc = lane & 15;
    #pragma unroll
    for (int i = 0; i < 4; ++i) {
        const int grow = m0 + wm + i * 16 + cr;
        #pragma unroll
        for (int j = 0; j < 4; ++j) {
            const int gcol = n0 + wn + j * 16 + cc;
            const float bb = bias ? bias[gcol] : 0.f;
            float* cp = C + (size_t)grow * ldc + gcol;
            #pragma unroll
            for (int r = 0; r < 4; ++r)
                cp[(size_t)r * ldc] = acc[i][j][r] + bb;
        }
    }
}

// ---------------------------------------------------------------------------
// Generic tiled fp32 GEMM: C(MxN) = A(MxK) @ B(NxK)^T (+ bias[col])
// ---------------------------------------------------------------------------
__global__ __launch_bounds__(256)
void gemm_abt(const float* __restrict__ A, int lda,
              const float* __restrict__ B, int ldb,
              float* __restrict__ C, int ldc,
              int M, int N, int K,
              const float* __restrict__ bias,
              int aZ, int bZ, int cZ)
{
    __shared__ float As[16][68];
    __shared__ float Bs[16][68];
    A += (size_t)blockIdx.z * aZ;
    B += (size_t)blockIdx.z * bZ;
    C += (size_t)blockIdx.z * cZ;
    const int m0 = blockIdx.y * 64;
    const int n0 = blockIdx.x * 64;
    const int tid = threadIdx.x;
    const int tm = tid >> 4;
    const int tn = tid & 15;
    const int lr = tid >> 2;
    const int lc = (tid & 3) << 2;

    float acc[4][4] = {};

    for (int k0 = 0; k0 < K; k0 += 16) {
        float4 av = make_float4(0.f, 0.f, 0.f, 0.f);
        float4 bv = make_float4(0.f, 0.f, 0.f, 0.f);
        const int am = m0 + lr;
        if (am < M) av = *(const float4*)(A + (size_t)am * lda + k0 + lc);
        const int bn = n0 + lr;
        if (bn < N) bv = *(const float4*)(B + (size_t)bn * ldb + k0 + lc);
        As[lc + 0][lr] = av.x; As[lc + 1][lr] = av.y;
        As[lc + 2][lr] = av.z; As[lc + 3][lr] = av.w;
        Bs[lc + 0][lr] = bv.x; Bs[lc + 1][lr] = bv.y;
        Bs[lc + 2][lr] = bv.z; Bs[lc + 3][lr] = bv.w;
        __syncthreads();
        #pragma unroll
        for (int k = 0; k < 16; ++k) {
            float a[4], b[4];
            #pragma unroll
            for (int i = 0; i < 4; ++i) a[i] = As[k][tm * 4 + i];
            #pragma unroll
            for (int j = 0; j < 4; ++j) b[j] = Bs[k][tn * 4 + j];
            #pragma unroll
            for (int i = 0; i < 4; ++i)
                #pragma unroll
                for (int j = 0; j < 4; ++j)
                    acc[i][j] += a[i] * b[j];
        }
        __syncthreads();
    }

    #pragma unroll
    for (int i = 0; i < 4; ++i) {
        const int row = m0 + tm * 4 + i;
        if (row >= M) continue;
        #pragma unroll
        for (int j = 0; j < 4; ++j) {
            const int col = n0 + tn * 4 + j;
            if (col < N) {
                float v = acc[i][j];
                if (bias) v += bias[col];
                C[(size_t)row * ldc + col] = v;
            }
        }
    }
}

// ---------------------------------------------------------------------------
// Small helpers
// ---------------------------------------------------------------------------
__device__ __forceinline__ float block_sum_256(float v, float* red)
{
    #pragma unroll
    for (int off = 32; off; off >>= 1) v += __shfl_down(v, off, 64);
    const int lane = threadIdx.x & 63, wid = threadIdx.x >> 6;
    __syncthreads();
    if (lane == 0) red[wid] = v;
    __syncthreads();
    return red[0] + red[1] + red[2] + red[3];
}

__global__ void zero_small(float* p, int n)
{
    int i = blockIdx.x * blockDim.x + threadIdx.x;
    if (i < n) p[i] = 0.f;
}

// fp32 -> bf16 (RNE), n multiple of 4
__global__ void f32_to_bf16(const float* __restrict__ src,
                            unsigned short* __restrict__ dst, int n)
{
    int i = (blockIdx.x * blockDim.x + threadIdx.x) * 4;
    if (i >= n) return;
    float4 v = *(const float4*)(src + i);
    ushort4 o;
    o.x = f2bf(v.x); o.y = f2bf(v.y); o.z = f2bf(v.z); o.w = f2bf(v.w);
    *(ushort4*)(dst + i) = o;
}

__global__ void prep_key_norm(const float* __restrict__ km, float* __restrict__ kn)
{
    const int row = blockIdx.x;
    const int lane = threadIdx.x;      // 64 threads
    float v = km[(size_t)row * HD + lane];
    float s = v * v;
    #pragma unroll
    for (int off = 32; off; off >>= 1) s += __shfl_down(s, off, 64);
    s = __shfl(s, 0, 64);
    const float inv = 1.f / fmaxf(sqrtf(s), 1e-12f);
    kn[(size_t)row * HD + lane] = v * inv;
}

__global__ void prep_value_norm(const float* __restrict__ vm,
                                float* __restrict__ vn, float* __restrict__ vmT)
{
    const int row = blockIdx.x;        // 0..111
    const int tid = threadIdx.x;       // 256
    __shared__ float red[4];
    const float v0 = vm[(size_t)row * DIMC + tid];
    const float v1 = vm[(size_t)row * DIMC + 256 + tid];
    const float tot = block_sum_256(v0 * v0 + v1 * v1, red);
    const float inv = 1.f / fmaxf(sqrtf(tot), 1e-12f);
    vn[(size_t)row * DIMC + tid]        = v0 * inv;
    vn[(size_t)row * DIMC + 256 + tid]  = v1 * inv;
    vmT[(size_t)tid * SLOTS + row]         = v0;
    vmT[(size_t)(256 + tid) * SLOTS + row] = v1;
}

__global__ void contrastive_kernel(const float* __restrict__ vn, float* __restrict__ outc)
{
    __shared__ float vni[DIMC];
    __shared__ float red[2];
    const int i = blockIdx.x, tid = threadIdx.x;   // 128 threads
    for (int d = tid; d < DIMC; d += 128) vni[d] = vn[(size_t)i * DIMC + d];
    __syncthreads();
    float t = 0.f;
    if (tid < SLOTS) {
        const float* r = vn + (size_t)tid * DIMC;
        float dot = 0.f;
        for (int d = 0; d < DIMC; ++d) dot += vni[d] * r[d];
        const float delta = (tid == i) ? 1.f : 0.f;
        t = fabsf(delta - dot);
    }
    #pragma unroll
    for (int off = 32; off; off >>= 1) t += __shfl_down(t, off, 64);
    if ((tid & 63) == 0) red[tid >> 6] = t;
    __syncthreads();
    if (tid == 0) atomicAdd(outc, 0.5f * (red[0] + red[1]));
}

// Per-(row,head) inverse l2 norm of eq
__global__ __launch_bounds__(256)
void eq_head_norms(const float* __restrict__ eq, float* __restrict__ hinv)
{
    const int wid  = threadIdx.x >> 6;
    const int lane = threadIdx.x & 63;
    const int r = blockIdx.x * 4 + wid;
    const float4 v0 = *(const float4*)(eq + (size_t)r * DIMC + lane * 8);
    const float4 v1 = *(const float4*)(eq + (size_t)r * DIMC + lane * 8 + 4);
    float s = v0.x * v0.x + v0.y * v0.y + v0.z * v0.z + v0.w * v0.w
            + v1.x * v1.x + v1.y * v1.y + v1.z * v1.z + v1.w * v1.w;
    s += __shfl_down(s, 4, 8);
    s += __shfl_down(s, 2, 8);
    s += __shfl_down(s, 1, 8);
    if ((lane & 7) == 0)
        hinv[(size_t)r * HEADS + (lane >> 3)] = 1.f / fmaxf(sqrtf(s), 1e-12f);
}

// Per-row inverse l2 norm over 512 floats (one wave per row)
__global__ __launch_bounds__(256)
void row_rnorm(const float* __restrict__ x, float* __restrict__ rinv)
{
    const int wave = threadIdx.x >> 6, lane = threadIdx.x & 63;
    const int r = blockIdx.x * 4 + wave;
    const float* p = x + (size_t)r * DIMC + lane * 8;
    const float4 a = *(const float4*)p;
    const float4 b = *(const float4*)(p + 4);
    float s = a.x * a.x + a.y * a.y + a.z * a.z + a.w * a.w
            + b.x * b.x + b.y * b.y + b.z * b.z + b.w * b.w;
    #pragma unroll
    for (int off = 32; off; off >>= 1) s += __shfl_down(s, off, 64);
    if (lane == 0) rinv[r] = 1.f / fmaxf(sqrtf(s), 1e-12f);
}

// Per-head softmax over 112 slots of sim row (scaled by RADIUS*hinv),
// bf16 output in place over the same row slot (see round-4 notes).
__global__ __launch_bounds__(256)
void key_softmax(const float* __restrict__ sim, unsigned short* __restrict__ kadd,
                 const float* __restrict__ hinv)
{
    const int r = blockIdx.x, tid = threadIdx.x;
    const int g = tid >> 5, li = tid & 31;
    const float scale = RADIUSF * hinv[(size_t)r * HEADS + g];
    const float* row = sim + (size_t)r * (HEADS * SLOTS) + g * SLOTS;
    unsigned short* orow = kadd + (size_t)r * (2 * HEADS * SLOTS) + g * SLOTS;

    float v[4];
    #pragma unroll
    for (int u = 0; u < 4; ++u) {
        const int s = li + u * 32;
        v[u] = (s < SLOTS) ? row[s] * scale : -1e30f;
    }
    __syncthreads();   // all reads of this row done before any bf16 write
    float mx = fmaxf(fmaxf(v[0], v[1]), fmaxf(v[2], v[3]));
    #pragma unroll
    for (int off = 16; off; off >>= 1) mx = fmaxf(mx, __shfl_down(mx, off, 32));
    mx = __shfl(mx, 0, 32);
    float e[4]; float sum = 0.f;
    #pragma unroll
    for (int u = 0; u < 4; ++u) {
        const int s = li + u * 32;
        e[u] = (s < SLOTS) ? __expf(v[u] - mx) : 0.f;
        sum += e[u];
    }
    #pragma unroll
    for (int off = 16; off; off >>= 1) sum += __shfl_down(sum, off, 32);
    sum = __shfl(sum, 0, 32);
    const float invs = 1.f / sum;
    #pragma unroll
    for (int u = 0; u < 4; ++u) {
        const int s = li + u * 32;
        if (s < SLOTS) orow[s] = f2bf(e[u] * invs);
    }
}

// Wave-per-row: vir_pre -> LN(g2,b2) -> +query -> LN(g1,b1) -> out_te
__global__ __launch_bounds__(256)
void vir_te_w(const float* __restrict__ vir_pre, const float* __restrict__ query,
              const float* __restrict__ g1, const float* __restrict__ b1,
              const float* __restrict__ g2, const float* __restrict__ b2,
              float* __restrict__ out_te)
{
    const int wave = threadIdx.x >> 6, lane = threadIdx.x & 63;
    const int r = blockIdx.x * 4 + wave;
    const size_t base = (size_t)r * DIMC + lane * 8;
    const float4 xa = *(const float4*)(vir_pre + base);
    const float4 xb = *(const float4*)(vir_pre + base + 4);
    const float4 qa = *(const float4*)(query + base);
    const float4 qb = *(const float4*)(query + base + 4);
    float x[8] = {xa.x, xa.y, xa.z, xa.w, xb.x, xb.y, xb.z, xb.w};
    float q[8] = {qa.x, qa.y, qa.z, qa.w, qb.x, qb.y, qb.z, qb.w};

    float s1 = 0.f, s2 = 0.f;
    #pragma unroll
    for (int i = 0; i < 8; ++i) { s1 += x[i]; s2 += x[i] * x[i]; }
    wred2(s1, s2);
    float mu = s1 * (1.f / DIMC);
    float var = s2 * (1.f / DIMC) - mu * mu;
    float rstd = rsqrtf(var + 1e-5f);

    float y[8]; float t1 = 0.f, t2 = 0.f;
    #pragma unroll
    for (int i = 0; i < 8; ++i) {
        const int c = lane * 8 + i;
        const float v = (x[i] - mu) * rstd * g2[c] + b2[c];
        y[i] = q[i] + v;
        t1 += y[i]; t2 += y[i] * y[i];
    }
    wred2(t1, t2);
    mu = t1 * (1.f / DIMC);
    var = t2 * (1.f / DIMC) - mu * mu;
    rstd = rsqrtf(var + 1e-5f);

    float o[8];
    #pragma unroll
    for (int i = 0; i < 8; ++i) {
        const int c = lane * 8 + i;
        o[i] = (y[i] - mu) * rstd * g1[c] + b1[c];
    }
    *(float4*)(out_te + base)     = make_float4(o[0], o[1], o[2], o[3]);
    *(float4*)(out_te + base + 4) = make_float4(o[4], o[5], o[6], o[7]);
}

// Wave-per-row softmax(RADIUS * rinv[r] * sim) over 112 slots, in place.
__global__ __launch_bounds__(256)
void value_softmax_w(float* __restrict__ vs, const float* __restrict__ rinv)
{
    const int wave = threadIdx.x >> 6, lane = threadIdx.x & 63;
    const int r = blockIdx.x * 4 + wave;
    const float scale = RADIUSF * rinv[r];
    float* row = vs + (size_t)r * SLOTS;
    const float v0 = row[lane] * scale;
    const float v1 = (lane < 48) ? row[64 + lane] * scale : -1e30f;
    float m = fmaxf(v0, v1);
    #pragma unroll
    for (int off = 32; off; off >>= 1) m = fmaxf(m, __shfl_down(m, off, 64));
    m = __shfl(m, 0, 64);
    const float e0 = __expf(v0 - m);
    const float e1 = (lane < 48) ? __expf(v1 - m) : 0.f;
    float s = e0 + e1;
    #pragma unroll
    for (int off = 32; off; off >>= 1) s += __shfl_down(s, off, 64);
    s = __shfl(s, 0, 64);
    const float inv = 1.f / s;
    row[lane] = e0 * inv;
    if (lane < 48) row[64 + lane] = e1 * inv;
}

// Wave-per-row: cos/recon, LN(g3,b3), +query, LN(g1,b1) -> out_tr.
// One recon atomic per block (4 rows share the same batch index).
__global__ __launch_bounds__(256)
void aud_epilogue_w(const float* __restrict__ aud, const float* __restrict__ value,
                    const float* __restrict__ query,
                    const float* __restrict__ g1, const float* __restrict__ b1,
                    const float* __restrict__ g3, const float* __restrict__ b3,
                    float* __restrict__ out_tr, float* __restrict__ recon)
{
    __shared__ float red[4];
    const int wave = threadIdx.x >> 6, lane = threadIdx.x & 63;
    const int r = blockIdx.x * 4 + wave;
    const size_t base = (size_t)r * DIMC + lane * 8;
    const float4 aa = *(const float4*)(aud + base);
    const float4 ab = *(const float4*)(aud + base + 4);
    const float4 va = *(const float4*)(value + base);
    const float4 vb = *(const float4*)(value + base + 4);
    const float4 qa = *(const float4*)(query + base);
    const float4 qb = *(const float4*)(query + base + 4);
    float a[8] = {aa.x, aa.y, aa.z, aa.w, ab.x, ab.y, ab.z, ab.w};
    float v[8] = {va.x, va.y, va.z, va.w, vb.x, vb.y, vb.z, vb.w};
    float q[8] = {qa.x, qa.y, qa.z, qa.w, qb.x, qb.y, qb.z, qb.w};

    float dot = 0.f, na = 0.f, nv = 0.f, s1 = 0.f;
    #pragma unroll
    for (int i = 0; i < 8; ++i) {
        dot += a[i] * v[i];
        na  += a[i] * a[i];
        nv  += v[i] * v[i];
        s1  += a[i];
    }
    wred4(dot, na, nv, s1);                    // na == sum(a^2)
    const float cosv = dot / fmaxf(sqrtf(na) * sqrtf(nv), 1e-8f);
    if (lane == 0) red[wave] = fabsf(1.f - cosv);

    float mu = s1 * (1.f / DIMC);
    float var = na * (1.f / DIMC) - mu * mu;
    float rstd = rsqrtf(var + 1e-5f);

    float y[8]; float t1 = 0.f, t2 = 0.f;
    #pragma unroll
    for (int i = 0; i < 8; ++i) {
        const int c = lane * 8 + i;
        const float w = (a[i] - mu) * rstd * g3[c] + b3[c];
        y[i] = q[i] + w;
        t1 += y[i]; t2 += y[i] * y[i];
    }
    wred2(t1, t2);
    mu = t1 * (1.f / DIMC);
    var = t2 * (1.f / DIMC) - mu * mu;
    rstd = rsqrtf(var + 1e-5f);

    float o[8];
    #pragma unroll
    for (int i = 0; i < 8; ++i) {
        const int c = lane * 8 + i;
        o[i] = (y[i] - mu) * rstd * g1[c] + b1[c];
    }
    *(float4*)(out_tr + base)     = make_float4(o[0], o[1], o[2], o[3]);
    *(float4*)(out_tr + base + 4) = make_float4(o[4], o[5], o[6], o[7]);

    __syncthreads();
    if (threadIdx.x == 0)
        atomicAdd(&recon[r >> 9], red[0] + red[1] + red[2] + red[3]);
}

// ---------------------------------------------------------------------------
// Launch
// ---------------------------------------------------------------------------
extern "C" void kernel_launch(void* const* d_in, const int* in_sizes, int n_in,
                              void* d_out, int out_size, void* d_ws, size_t ws_size,
                              hipStream_t stream)
{
    const float* query = (const float*)d_in[0];
    const float* value = (const float*)d_in[1];
    const float* keym  = (const float*)d_in[2];
    const float* vmem  = (const float*)d_in[3];
    const float* Wq    = (const float*)d_in[4];
    const float* bq    = (const float*)d_in[5];
    const float* Wv    = (const float*)d_in[6];
    const float* bv    = (const float*)d_in[7];
    const float* Wl    = (const float*)d_in[8];
    const float* bl    = (const float*)d_in[9];
    const float* g1    = (const float*)d_in[10];
    const float* b1    = (const float*)d_in[11];
    const float* g2    = (const float*)d_in[12];
    const float* b2    = (const float*)d_in[13];
    const float* g3    = (const float*)d_in[14];
    const float* b3    = (const float*)d_in[15];

    float* out    = (float*)d_out;
    float* out_te = out;
    float* out_tr = out + 8388608;
    float* out_rc = out + 16777216;    // 32 recon + 1 contrastive

    // Workspace layout (float offsets). Total 34,054,144 floats = 136.2 MB.
    float* ws = (float*)d_ws;
    float* w_kn   = ws + 0;         //   896*64
    float* w_vn   = ws + 57344;     //   112*512
    float* w_vmT  = ws + 114688;    //   512*112
    float* w_W2T  = ws + 172032;    //   512*896 fp32
    float* w_hinv = ws + 630784;    // 16384*8
    float* w_eq   = ws + 761856;    // 16384*512 fp32 (eq -> vir_pre)
    float* w_sims = ws + 9150464;   // 16384*896 fp32 [9150464, 23830528)
    float* w_ev   = ws + 23830528;  // 16384*512 fp32 [23830528, 32219136) (ev -> aud)
    float* w_vs   = ws + 32219136;  // 16384*112 fp32

    // bf16 staging aliases (lifetimes verified against stream order, round 4):
    unsigned short* w_qbf   = (unsigned short*)(ws + 23830528); // in w_ev region
    unsigned short* w_wqbf  = (unsigned short*)(ws + 28024832);
    unsigned short* w_w2tbf = (unsigned short*)(ws + 28155904);
    unsigned short* w_kadd  = (unsigned short*)(ws + 9150464);  // in place over sims
    unsigned short* w_vbf   = (unsigned short*)(ws + 9150464);  // sims region, dead post-vir
    unsigned short* w_wvbf  = (unsigned short*)(ws + 13344768);
    float*          w_rinv  = ws + 13475840;                    // 16384 fp32, sims region

    // 0) zero recon+contrastive
    zero_small<<<1, 64, 0, stream>>>(out_rc, 33);

    // 1) input-only precomputes
    prep_key_norm<<<896, 64, 0, stream>>>(keym, w_kn);
    prep_value_norm<<<112, 256, 0, stream>>>(vmem, w_vn, w_vmT);
    contrastive_kernel<<<112, 128, 0, stream>>>(w_vn, out_rc + 32);
    gemm_abt<<<dim3(2, 8, 8), 256, 0, stream>>>(              // W2T fp32
        Wl, 4096, vmem, DIMC, w_W2T, HEADS * SLOTS,
        DIMC, SLOTS, DIMC, nullptr, DIMC, 0, SLOTS);
    f32_to_bf16<<<448, 256, 0, stream>>>(w_W2T, w_w2tbf, DIMC * HEADS * SLOTS);

    // 2) key addressing path
    f32_to_bf16<<<8192, 256, 0, stream>>>(query, w_qbf, NROWS * DIMC);
    f32_to_bf16<<<256, 256, 0, stream>>>(Wq, w_wqbf, DIMC * DIMC);
    gemm_bf16<<<dim3(4, 128), 256, 0, stream>>>(              // eq = q@Wq^T + bq
        (const short*)w_qbf, DIMC, (const short*)w_wqbf, DIMC,
        w_eq, DIMC, DIMC, bq);
    eq_head_norms<<<NROWS / 4, 256, 0, stream>>>(w_eq, w_hinv);
    gemm_abt<<<dim3(2, 256, 8), 256, 0, stream>>>(            // sims (fp32)
        w_eq, DIMC, w_kn, HD, w_sims, HEADS * SLOTS,
        NROWS, SLOTS, HD, nullptr, HD, SLOTS * HD, SLOTS);
    key_softmax<<<NROWS, 256, 0, stream>>>(w_sims, w_kadd, w_hinv);
    gemm_bf16<<<dim3(4, 128), 256, 0, stream>>>(              // vir_pre = kadd@W2T^T + bl
        (const short*)w_kadd, 2 * HEADS * SLOTS, (const short*)w_w2tbf, HEADS * SLOTS,
        w_eq, DIMC, HEADS * SLOTS, bl);
    vir_te_w<<<NROWS / 4, 256, 0, stream>>>(w_eq, query, g1, b1, g2, b2, out_te);

    // 3) value addressing path (vbf/wvbf/rinv live in dead sims region)
    f32_to_bf16<<<8192, 256, 0, stream>>>(value, w_vbf, NROWS * DIMC);
    f32_to_bf16<<<256, 256, 0, stream>>>(Wv, w_wvbf, DIMC * DIMC);
    gemm_bf16<<<dim3(4, 128), 256, 0, stream>>>(              // ev = v@Wv^T + bv
        (const short*)w_vbf, DIMC, (const short*)w_wvbf, DIMC,
        w_ev, DIMC, DIMC, bv);
    row_rnorm<<<NROWS / 4, 256, 0, stream>>>(w_ev, w_rinv);   // replaces l2norm round-trip
    gemm_abt<<<dim3(2, 256, 1), 256, 0, stream>>>(            // value_sim on RAW ev (fp32)
        w_ev, DIMC, w_vn, DIMC, w_vs, SLOTS,
        NROWS, SLOTS, DIMC, nullptr, 0, 0, 0);
    value_softmax_w<<<NROWS / 4, 256, 0, stream>>>(w_vs, w_rinv);
    gemm_abt<<<dim3(8, 256, 1), 256, 0, stream>>>(            // aud (fp32)
        w_vs, SLOTS, w_vmT, SLOTS, w_ev, DIMC,
        NROWS, DIMC, SLOTS, nullptr, 0, 0, 0);
    aud_epilogue_w<<<NROWS / 4, 256, 0, stream>>>(
        w_ev, value, query, g1, b1, g3, b3, out_tr, out_rc);
}